// Round 1
// baseline (618.347 us; speedup 1.0000x reference)
//
#include <hip/hip_runtime.h>
#include <stdint.h>

#define B_ 2
#define S_ 2048
#define C_ 768
#define H_ 8
#define DH 96
#define CTX 128
#define I_ 3072
#define M_ (B_*S_)
#define N3 (3*C_)

typedef unsigned short u16;
typedef __bf16 bf16x8 __attribute__((ext_vector_type(8)));
typedef float f32x4 __attribute__((ext_vector_type(4)));

__device__ __forceinline__ u16 f2b(float f){
  union { float f; uint32_t u; } v; v.f = f;
  uint32_t r = (v.u + 0x7FFFu + ((v.u >> 16) & 1u)) >> 16;
  return (u16)r;
}
__device__ __forceinline__ float b2f(u16 h){
  union { uint32_t u; float f; } v; v.u = ((uint32_t)h) << 16;
  return v.f;
}
__device__ __forceinline__ void gload_lds16(const void* g, void* l){
  __builtin_amdgcn_global_load_lds((const __attribute__((address_space(1))) void*)g,
                                   (__attribute__((address_space(3))) void*)l, 16, 0, 0);
}

// ---------------- weight convert+transpose: W (K,N) f32 -> Wt (N,K) bf16 ----------------
__global__ void wconv_kernel(const float* __restrict__ Wsrc, u16* __restrict__ Wt, int K, int N){
  __shared__ float tile[32][33];
  const int n0 = blockIdx.x*32, k0 = blockIdx.y*32;
  const int tx = threadIdx.x & 31, ty = threadIdx.x >> 5;
  #pragma unroll
  for(int i=0;i<4;i++)
    tile[ty + i*8][tx] = Wsrc[(size_t)(k0 + ty + i*8) * N + n0 + tx];
  __syncthreads();
  #pragma unroll
  for(int i=0;i<4;i++)
    Wt[(size_t)(n0 + ty + i*8) * K + k0 + tx] = f2b(tile[tx][ty + i*8]);
}

// ---------------- f32 -> bf16 ----------------
__global__ void cvt_kernel(const float* __restrict__ in, u16* __restrict__ out, int n){
  int i = blockIdx.x*256 + threadIdx.x;
  if(i < n) out[i] = f2b(in[i]);
}

// ---------------- LayerNorm over rows of 768, bf16 out ----------------
__global__ __launch_bounds__(256) void ln_kernel(const float* __restrict__ x, const float* __restrict__ g,
    const float* __restrict__ bb, u16* __restrict__ out)
{
  const int row = blockIdx.x;
  const int t = threadIdx.x;
  const float* xr = x + (size_t)row * C_;
  float v0 = xr[t], v1 = xr[t+256], v2 = xr[t+512];
  float s = v0+v1+v2;
  float s2 = v0*v0 + v1*v1 + v2*v2;
  #pragma unroll
  for(int off=32; off>0; off>>=1){ s += __shfl_down(s, off); s2 += __shfl_down(s2, off); }
  __shared__ float red[8];
  const int lane = t & 63, wv = t >> 6;
  if(lane == 0){ red[wv] = s; red[4+wv] = s2; }
  __syncthreads();
  s = red[0]+red[1]+red[2]+red[3];
  s2 = red[4]+red[5]+red[6]+red[7];
  const float mu = s * (1.0f/C_);
  const float inv = rsqrtf(s2*(1.0f/C_) - mu*mu + 1e-5f);
  u16* orow = out + (size_t)row*C_;
  orow[t]     = f2b((v0-mu)*inv*g[t]     + bb[t]);
  orow[t+256] = f2b((v1-mu)*inv*g[t+256] + bb[t+256]);
  orow[t+512] = f2b((v2-mu)*inv*g[t+512] + bb[t+512]);
}

// ---------------- GEMM: A (M,K) bf16 @ Bt (N,K) bf16 -> bf16 out or f32(acc+resid) ----------------
__global__ __launch_bounds__(256) void gemm_kernel(
    const u16* __restrict__ A, const u16* __restrict__ Bt,
    u16* __restrict__ Ob, float* __restrict__ Of, const float* __restrict__ resid,
    int Mdim, int Ndim, int Kdim, int outF32)
{
  __shared__ __align__(16) u16 As[128*32];
  __shared__ __align__(16) u16 Bs[128*32];
  const int tid = threadIdx.x;
  const int lane = tid & 63, w = tid >> 6;
  const int wm = w >> 1, wn = w & 1;
  const int m0 = blockIdx.y * 128, n0 = blockIdx.x * 128;
  f32x4 acc[4][4] = {};
  const int sr = tid >> 2;            // staging row 0..63
  const int sc = (tid & 3) << 3;      // staging col (elems)
  const int l15 = lane & 15, lk = (lane >> 4) << 3;
  for(int k0 = 0; k0 < Kdim; k0 += 32){
    #pragma unroll
    for(int j = 0; j < 2; j++){
      gload_lds16(A  + (size_t)(m0 + sr + (j<<6)) * Kdim + k0 + sc, As + (tid<<3) + (j<<11));
      gload_lds16(Bt + (size_t)(n0 + sr + (j<<6)) * Kdim + k0 + sc, Bs + (tid<<3) + (j<<11));
    }
    __syncthreads();
    bf16x8 af[4], bfr[4];
    #pragma unroll
    for(int i=0;i<4;i++) af[i]  = *(const bf16x8*)(As + (wm*64 + i*16 + l15)*32 + lk);
    #pragma unroll
    for(int i=0;i<4;i++) bfr[i] = *(const bf16x8*)(Bs + (wn*64 + i*16 + l15)*32 + lk);
    #pragma unroll
    for(int mi=0;mi<4;mi++)
      #pragma unroll
      for(int ni=0;ni<4;ni++)
        acc[mi][ni] = __builtin_amdgcn_mfma_f32_16x16x32_bf16(af[mi], bfr[ni], acc[mi][ni], 0,0,0);
    __syncthreads();
  }
  const int rbase = m0 + wm*64 + ((lane>>4)<<2);
  const int cbase = n0 + wn*64 + l15;
  if(outF32){
    #pragma unroll
    for(int mi=0;mi<4;mi++)
      #pragma unroll
      for(int ni=0;ni<4;ni++)
        #pragma unroll
        for(int r=0;r<4;r++){
          size_t idx = (size_t)(rbase + mi*16 + r) * Ndim + cbase + ni*16;
          Of[idx] = acc[mi][ni][r] + resid[idx];
        }
  } else {
    #pragma unroll
    for(int mi=0;mi<4;mi++)
      #pragma unroll
      for(int ni=0;ni<4;ni++)
        #pragma unroll
        for(int r=0;r<4;r++){
          size_t idx = (size_t)(rbase + mi*16 + r) * Ndim + cbase + ni*16;
          Ob[idx] = f2b(acc[mi][ni][r]);
        }
  }
}

// ---------------- RoPE in-place on q,k slices of qkv (bf16) ----------------
__global__ void rope_kernel(u16* qkv, const int* hp, const int* wp){
  const int W = wp[0], HH = hp[0];
  int idx = blockIdx.x*256 + threadIdx.x;
  if(idx >= M_*H_*48) return;
  const int d = idx % 48;
  int t1 = idx / 48;
  const int h = t1 & 7;
  const int m = t1 >> 3;
  const int s = m & (S_-1);
  const int xc = s % W;
  const int y  = (s / W) % HH;
  const int tf = s / (W*HH);
  float pos1, pos2;
  {
    int blk1 = d >> 5;            // 0 or 1
    int blk2 = (d+48) >> 5;       // 1 or 2
    pos1 = (float)(blk1==0 ? xc : (blk1==1 ? y : tf));
    pos2 = (float)(blk2==0 ? xc : (blk2==1 ? y : tf));
  }
  float a1 = pos1 * __powf(10000.0f, -(float)(d & 15) * (1.0f/16.0f));
  float a2 = pos2 * __powf(10000.0f, -(float)((d+48) & 15) * (1.0f/16.0f));
  float s1, c1, s2, c2;
  __sincosf(a1, &s1, &c1);
  __sincosf(a2, &s2, &c2);
  size_t base = (size_t)m * N3 + h*DH;
  #pragma unroll
  for(int part=0; part<2; part++){
    u16* p = qkv + base + (size_t)part*C_;
    float x1 = b2f(p[d]), x2 = b2f(p[d+48]);
    p[d]    = f2b(x1*c1 - x2*s1);
    p[d+48] = f2b(x2*c2 + x1*s2);
  }
}

// ---------------- V transpose: src rows (b*seq+s, stride) col (colOff+h*DH+d) -> dst[(bh*DH+d)*seq + s] ----------------
__global__ __launch_bounds__(256) void vt_kernel(const u16* __restrict__ src, u16* __restrict__ dst,
                                                 int rowStride, int colOff, int seqLen){
  const int bh = blockIdx.y, b = bh >> 3, h = bh & 7;
  const int s0 = blockIdx.x*64;
  __shared__ u16 t[64][DH+8];
  const int tid = threadIdx.x;
  #pragma unroll
  for(int i=0;i<24;i++){
    int e = tid + i*256; int si = e/DH, d = e - si*DH;
    t[si][d] = src[(size_t)(b*seqLen + s0+si)*rowStride + colOff + h*DH + d];
  }
  __syncthreads();
  #pragma unroll
  for(int i=0;i<24;i++){
    int e = tid + i*256; int d = e >> 6, si = e & 63;
    dst[((size_t)bh*DH + d)*seqLen + s0 + si] = t[si][d];
  }
}

// ---------------- Flash attention (self w/ causal, or cross) ----------------
__global__ __launch_bounds__(256) void attn_kernel(
    const u16* __restrict__ qp, int qStride, int qOff,
    const u16* __restrict__ kp, int kStride, int kOff,
    const u16* __restrict__ vt,   // (bh, DH, kvLen)
    u16* __restrict__ op,         // (B*S, C) at col h*DH
    int kvLen, int causal)
{
  const int bh = blockIdx.y, b = bh >> 3, h = bh & 7;
  const int q0 = blockIdx.x * 64;
  const int lane = threadIdx.x & 63, w = threadIdx.x >> 6;
  const int l15 = lane & 15, lg = lane >> 4, lk = lg << 3;
  const int qrow_base = q0 + w*16;
  const float scale = 0.1020620726159658f;  // 96^-0.5
  __shared__ __align__(16) u16 Plds[4][16][64];
  bf16x8 qf[3];
  {
    const size_t qb = (size_t)(b*S_ + qrow_base + l15) * qStride + qOff + h*DH;
    #pragma unroll
    for(int ks=0;ks<3;ks++) qf[ks] = *(const bf16x8*)(qp + qb + ks*32 + lk);
  }
  f32x4 oacc[6] = {};
  float mrow[4], lrow[4];
  #pragma unroll
  for(int r=0;r<4;r++){ mrow[r] = -3e38f; lrow[r] = 0.f; }
  const int kvEnd = causal ? (q0 + 64) : kvLen;
  for(int kv0 = 0; kv0 < kvEnd; kv0 += 64){
    f32x4 sacc[4] = {};
    #pragma unroll
    for(int nt=0;nt<4;nt++){
      const size_t kb = (size_t)(b*kvLen + kv0 + nt*16 + l15) * kStride + kOff + h*DH;
      #pragma unroll
      for(int ks=0;ks<3;ks++){
        bf16x8 kf = *(const bf16x8*)(kp + kb + ks*32 + lk);
        sacc[nt] = __builtin_amdgcn_mfma_f32_16x16x32_bf16(qf[ks], kf, sacc[nt], 0,0,0);
      }
    }
    const bool doMask = (causal != 0) && (kv0 + 64 > qrow_base);
    float mt[4];
    #pragma unroll
    for(int r=0;r<4;r++) mt[r] = -3e38f;
    #pragma unroll
    for(int nt=0;nt<4;nt++)
      #pragma unroll
      for(int r=0;r<4;r++){
        float v = sacc[nt][r] * scale;
        if(doMask && (kv0 + nt*16 + l15 > qrow_base + (lg<<2) + r)) v = -3e38f;
        sacc[nt][r] = v;
        mt[r] = fmaxf(mt[r], v);
      }
    #pragma unroll
    for(int r=0;r<4;r++){
      #pragma unroll
      for(int off=1; off<16; off<<=1) mt[r] = fmaxf(mt[r], __shfl_xor(mt[r], off));
    }
    float al[4], rs[4];
    #pragma unroll
    for(int r=0;r<4;r++){
      float mn = fmaxf(mrow[r], mt[r]);
      al[r] = __expf(mrow[r] - mn);
      mrow[r] = mn;
      rs[r] = 0.f;
    }
    #pragma unroll
    for(int nt=0;nt<4;nt++)
      #pragma unroll
      for(int r=0;r<4;r++){
        float pv = __expf(sacc[nt][r] - mrow[r]);
        sacc[nt][r] = pv;
        rs[r] += pv;
      }
    #pragma unroll
    for(int r=0;r<4;r++){
      #pragma unroll
      for(int off=1; off<16; off<<=1) rs[r] += __shfl_xor(rs[r], off);
      lrow[r] = lrow[r]*al[r] + rs[r];
    }
    #pragma unroll
    for(int n=0;n<6;n++)
      #pragma unroll
      for(int r=0;r<4;r++) oacc[n][r] *= al[r];
    #pragma unroll
    for(int nt=0;nt<4;nt++)
      #pragma unroll
      for(int r=0;r<4;r++)
        Plds[w][(lg<<2)+r][nt*16+l15] = f2b(sacc[nt][r]);
    #pragma unroll
    for(int kk=0;kk<2;kk++){
      bf16x8 pf = *(const bf16x8*)(&Plds[w][l15][kk*32 + lk]);
      #pragma unroll
      for(int n=0;n<6;n++){
        const u16* vp = vt + ((size_t)bh*DH + n*16 + l15)*kvLen + kv0 + kk*32 + lk;
        bf16x8 vf = *(const bf16x8*)vp;
        oacc[n] = __builtin_amdgcn_mfma_f32_16x16x32_bf16(pf, vf, oacc[n], 0,0,0);
      }
    }
  }
  #pragma unroll
  for(int n=0;n<6;n++)
    #pragma unroll
    for(int r=0;r<4;r++){
      const int qq = qrow_base + (lg<<2) + r;
      op[(size_t)(b*S_ + qq)*C_ + h*DH + n*16 + l15] = f2b(oacc[n][r] / lrow[r]);
    }
}

// ---------------- SiLU(gate) * up -> out (bf16) ----------------
__global__ void silu_kernel(const u16* gbuf, const u16* ubuf, u16* obuf, int n){
  int i = blockIdx.x*256 + threadIdx.x;
  if(i >= n) return;
  float xg = b2f(gbuf[i]), yu = b2f(ubuf[i]);
  float sg = 1.0f / (1.0f + __expf(-xg));
  obuf[i] = f2b(xg * sg * yu);
}

extern "C" void kernel_launch(void* const* d_in, const int* in_sizes, int n_in,
                              void* d_out, int out_size, void* d_ws, size_t ws_size,
                              hipStream_t stream)
{
  (void)in_sizes; (void)n_in; (void)out_size;
  const float* x    = (const float*)d_in[0];
  const float* ctxF = (const float*)d_in[1];
  const float* wqkvF= (const float*)d_in[2];
  const float* waoF = (const float*)d_in[3];
  const float* ln1g = (const float*)d_in[4];
  const float* ln1b = (const float*)d_in[5];
  const float* wqcF = (const float*)d_in[6];
  const float* wkcF = (const float*)d_in[7];
  const float* wvcF = (const float*)d_in[8];
  const float* wcoF = (const float*)d_in[9];
  const float* ln2g = (const float*)d_in[10];
  const float* ln2b = (const float*)d_in[11];
  const float* wgF  = (const float*)d_in[12];
  const float* wuF  = (const float*)d_in[13];
  const float* wdF  = (const float*)d_in[14];
  const float* ln3g = (const float*)d_in[15];
  const float* ln3b = (const float*)d_in[16];
  const int* hgt = (const int*)d_in[17];
  const int* wid = (const int*)d_in[18];
  float* out = (float*)d_out;

  char* base = (char*)d_ws;
  size_t off = 0;
  auto alloc = [&](size_t bytes)->void*{
    void* r = base + off;
    off += (bytes + 255) & ~(size_t)255;
    return r;
  };
  u16* wqkvT = (u16*)alloc((size_t)N3*C_*2);
  u16* waoT  = (u16*)alloc((size_t)C_*C_*2);
  u16* wqcT  = (u16*)alloc((size_t)C_*C_*2);
  u16* wkcT  = (u16*)alloc((size_t)C_*C_*2);
  u16* wvcT  = (u16*)alloc((size_t)C_*C_*2);
  u16* wcoT  = (u16*)alloc((size_t)C_*C_*2);
  u16* wgT   = (u16*)alloc((size_t)I_*C_*2);
  u16* wuT   = (u16*)alloc((size_t)I_*C_*2);
  u16* wdT   = (u16*)alloc((size_t)C_*I_*2);
  u16* ctxb  = (u16*)alloc((size_t)B_*CTX*C_*2);
  u16* xn    = (u16*)alloc((size_t)M_*C_*2);
  u16* qkvb  = (u16*)alloc((size_t)M_*N3*2);
  u16* vtb   = (u16*)alloc((size_t)B_*H_*DH*S_*2);
  u16* obuf  = (u16*)alloc((size_t)M_*C_*2);
  u16* qcb   = (u16*)alloc((size_t)M_*C_*2);
  u16* kcb   = (u16*)alloc((size_t)B_*CTX*C_*2);
  u16* vcb   = (u16*)alloc((size_t)B_*CTX*C_*2);
  u16* vctb  = (u16*)alloc((size_t)B_*H_*DH*CTX*2);
  u16* gateb = (u16*)alloc((size_t)M_*I_*2);
  u16* upb   = (u16*)alloc((size_t)M_*I_*2);
  float* x1  = (float*)alloc((size_t)M_*C_*4);
  float* x2  = (float*)alloc((size_t)M_*C_*4);
  if(off > ws_size) return;  // workspace too small -> visible failure

  dim3 blk(256);
  // weight conversion (bf16, transposed to (N,K))
  wconv_kernel<<<dim3(N3/32, C_/32), blk, 0, stream>>>(wqkvF, wqkvT, C_, N3);
  wconv_kernel<<<dim3(C_/32, C_/32), blk, 0, stream>>>(waoF, waoT, C_, C_);
  wconv_kernel<<<dim3(C_/32, C_/32), blk, 0, stream>>>(wqcF, wqcT, C_, C_);
  wconv_kernel<<<dim3(C_/32, C_/32), blk, 0, stream>>>(wkcF, wkcT, C_, C_);
  wconv_kernel<<<dim3(C_/32, C_/32), blk, 0, stream>>>(wvcF, wvcT, C_, C_);
  wconv_kernel<<<dim3(C_/32, C_/32), blk, 0, stream>>>(wcoF, wcoT, C_, C_);
  wconv_kernel<<<dim3(I_/32, C_/32), blk, 0, stream>>>(wgF, wgT, C_, I_);
  wconv_kernel<<<dim3(I_/32, C_/32), blk, 0, stream>>>(wuF, wuT, C_, I_);
  wconv_kernel<<<dim3(C_/32, I_/32), blk, 0, stream>>>(wdF, wdT, I_, C_);
  cvt_kernel<<<dim3((B_*CTX*C_+255)/256), blk, 0, stream>>>(ctxF, ctxb, B_*CTX*C_);

  // ---- self attention ----
  ln_kernel<<<dim3(M_), blk, 0, stream>>>(x, ln1g, ln1b, xn);
  gemm_kernel<<<dim3(N3/128, M_/128), blk, 0, stream>>>(xn, wqkvT, qkvb, nullptr, nullptr, M_, N3, C_, 0);
  rope_kernel<<<dim3((M_*H_*48+255)/256), blk, 0, stream>>>(qkvb, hgt, wid);
  vt_kernel<<<dim3(S_/64, B_*H_), blk, 0, stream>>>(qkvb, vtb, N3, 2*C_, S_);
  attn_kernel<<<dim3(S_/64, B_*H_), blk, 0, stream>>>(qkvb, N3, 0, qkvb, N3, C_, vtb, obuf, S_, 1);
  gemm_kernel<<<dim3(C_/128, M_/128), blk, 0, stream>>>(obuf, waoT, nullptr, x1, x, M_, C_, C_, 1);

  // ---- cross attention ----
  ln_kernel<<<dim3(M_), blk, 0, stream>>>(x1, ln2g, ln2b, xn);
  gemm_kernel<<<dim3(C_/128, M_/128), blk, 0, stream>>>(xn, wqcT, qcb, nullptr, nullptr, M_, C_, C_, 0);
  gemm_kernel<<<dim3(C_/128, (B_*CTX)/128), blk, 0, stream>>>(ctxb, wkcT, kcb, nullptr, nullptr, B_*CTX, C_, C_, 0);
  gemm_kernel<<<dim3(C_/128, (B_*CTX)/128), blk, 0, stream>>>(ctxb, wvcT, vcb, nullptr, nullptr, B_*CTX, C_, C_, 0);
  vt_kernel<<<dim3(CTX/64, B_*H_), blk, 0, stream>>>(vcb, vctb, C_, 0, CTX);
  attn_kernel<<<dim3(S_/64, B_*H_), blk, 0, stream>>>(qcb, C_, 0, kcb, C_, 0, vctb, obuf, CTX, 0);
  gemm_kernel<<<dim3(C_/128, M_/128), blk, 0, stream>>>(obuf, wcoT, nullptr, x2, x1, M_, C_, C_, 1);

  // ---- MLP ----
  ln_kernel<<<dim3(M_), blk, 0, stream>>>(x2, ln3g, ln3b, xn);
  gemm_kernel<<<dim3(I_/128, M_/128), blk, 0, stream>>>(xn, wgT, gateb, nullptr, nullptr, M_, I_, C_, 0);
  gemm_kernel<<<dim3(I_/128, M_/128), blk, 0, stream>>>(xn, wuT, upb, nullptr, nullptr, M_, I_, C_, 0);
  silu_kernel<<<dim3(M_*I_/256), blk, 0, stream>>>(gateb, upb, gateb, M_*I_);
  gemm_kernel<<<dim3(C_/128, M_/128), blk, 0, stream>>>(gateb, wdT, nullptr, out, x2, M_, C_, I_, 1);
}

// Round 2
// 485.042 us; speedup vs baseline: 1.2748x; 1.2748x over previous
//
#include <hip/hip_runtime.h>
#include <stdint.h>

#define B_ 2
#define S_ 2048
#define C_ 768
#define H_ 8
#define DH 96
#define CTX 128
#define I_ 3072
#define M_ (B_*S_)
#define N3 (3*C_)

typedef unsigned short u16;
typedef __bf16 bf16x8 __attribute__((ext_vector_type(8)));
typedef float f32x4 __attribute__((ext_vector_type(4)));

__device__ __forceinline__ u16 f2b(float f){
  union { float f; uint32_t u; } v; v.f = f;
  uint32_t r = (v.u + 0x7FFFu + ((v.u >> 16) & 1u)) >> 16;
  return (u16)r;
}
__device__ __forceinline__ float b2f(u16 h){
  union { uint32_t u; float f; } v; v.u = ((uint32_t)h) << 16;
  return v.f;
}
__device__ __forceinline__ void gload_lds16(const void* g, void* l){
  __builtin_amdgcn_global_load_lds((const __attribute__((address_space(1))) void*)g,
                                   (__attribute__((address_space(3))) void*)l, 16, 0, 0);
}

// ---------------- weight convert+transpose: W (K,N) f32 -> Wt (N,K) bf16 ----------------
__global__ void wconv_kernel(const float* __restrict__ Wsrc, u16* __restrict__ Wt, int K, int N){
  __shared__ float tile[32][33];
  const int n0 = blockIdx.x*32, k0 = blockIdx.y*32;
  const int tx = threadIdx.x & 31, ty = threadIdx.x >> 5;
  #pragma unroll
  for(int i=0;i<4;i++)
    tile[ty + i*8][tx] = Wsrc[(size_t)(k0 + ty + i*8) * N + n0 + tx];
  __syncthreads();
  #pragma unroll
  for(int i=0;i<4;i++)
    Wt[(size_t)(n0 + ty + i*8) * K + k0 + tx] = f2b(tile[tx][ty + i*8]);
}

// ---------------- f32 -> bf16 ----------------
__global__ void cvt_kernel(const float* __restrict__ in, u16* __restrict__ out, int n){
  int i = blockIdx.x*256 + threadIdx.x;
  if(i < n) out[i] = f2b(in[i]);
}

// ---------------- LayerNorm over rows of 768, bf16 out ----------------
__global__ __launch_bounds__(256) void ln_kernel(const float* __restrict__ x, const float* __restrict__ g,
    const float* __restrict__ bb, u16* __restrict__ out)
{
  const int row = blockIdx.x;
  const int t = threadIdx.x;
  const float* xr = x + (size_t)row * C_;
  float v0 = xr[t], v1 = xr[t+256], v2 = xr[t+512];
  float s = v0+v1+v2;
  float s2 = v0*v0 + v1*v1 + v2*v2;
  #pragma unroll
  for(int off=32; off>0; off>>=1){ s += __shfl_down(s, off); s2 += __shfl_down(s2, off); }
  __shared__ float red[8];
  const int lane = t & 63, wv = t >> 6;
  if(lane == 0){ red[wv] = s; red[4+wv] = s2; }
  __syncthreads();
  s = red[0]+red[1]+red[2]+red[3];
  s2 = red[4]+red[5]+red[6]+red[7];
  const float mu = s * (1.0f/C_);
  const float inv = rsqrtf(s2*(1.0f/C_) - mu*mu + 1e-5f);
  u16* orow = out + (size_t)row*C_;
  orow[t]     = f2b((v0-mu)*inv*g[t]     + bb[t]);
  orow[t+256] = f2b((v1-mu)*inv*g[t+256] + bb[t+256]);
  orow[t+512] = f2b((v2-mu)*inv*g[t+512] + bb[t+512]);
}

// ---------------- GEMM: A (M,K) bf16 @ Bt (N,K) bf16 -> bf16 out or f32(acc+resid) ----------------
__global__ __launch_bounds__(256) void gemm_kernel(
    const u16* __restrict__ A, const u16* __restrict__ Bt,
    u16* __restrict__ Ob, float* __restrict__ Of, const float* __restrict__ resid,
    int Mdim, int Ndim, int Kdim, int outF32)
{
  __shared__ __align__(16) u16 As[128*32];
  __shared__ __align__(16) u16 Bs[128*32];
  const int tid = threadIdx.x;
  const int lane = tid & 63, w = tid >> 6;
  const int wm = w >> 1, wn = w & 1;
  const int m0 = blockIdx.y * 128, n0 = blockIdx.x * 128;
  f32x4 acc[4][4] = {};
  const int sr = tid >> 2;            // staging row 0..63
  const int sc = (tid & 3) << 3;      // staging col (elems)
  const int l15 = lane & 15, lk = (lane >> 4) << 3;
  for(int k0 = 0; k0 < Kdim; k0 += 32){
    #pragma unroll
    for(int j = 0; j < 2; j++){
      gload_lds16(A  + (size_t)(m0 + sr + (j<<6)) * Kdim + k0 + sc, As + (tid<<3) + (j<<11));
      gload_lds16(Bt + (size_t)(n0 + sr + (j<<6)) * Kdim + k0 + sc, Bs + (tid<<3) + (j<<11));
    }
    __syncthreads();
    bf16x8 af[4], bfr[4];
    #pragma unroll
    for(int i=0;i<4;i++) af[i]  = *(const bf16x8*)(As + (wm*64 + i*16 + l15)*32 + lk);
    #pragma unroll
    for(int i=0;i<4;i++) bfr[i] = *(const bf16x8*)(Bs + (wn*64 + i*16 + l15)*32 + lk);
    #pragma unroll
    for(int mi=0;mi<4;mi++)
      #pragma unroll
      for(int ni=0;ni<4;ni++)
        acc[mi][ni] = __builtin_amdgcn_mfma_f32_16x16x32_bf16(af[mi], bfr[ni], acc[mi][ni], 0,0,0);
    __syncthreads();
  }
  const int rbase = m0 + wm*64 + ((lane>>4)<<2);
  const int cbase = n0 + wn*64 + l15;
  if(outF32){
    #pragma unroll
    for(int mi=0;mi<4;mi++)
      #pragma unroll
      for(int ni=0;ni<4;ni++)
        #pragma unroll
        for(int r=0;r<4;r++){
          size_t idx = (size_t)(rbase + mi*16 + r) * Ndim + cbase + ni*16;
          Of[idx] = acc[mi][ni][r] + resid[idx];
        }
  } else {
    #pragma unroll
    for(int mi=0;mi<4;mi++)
      #pragma unroll
      for(int ni=0;ni<4;ni++)
        #pragma unroll
        for(int r=0;r<4;r++){
          size_t idx = (size_t)(rbase + mi*16 + r) * Ndim + cbase + ni*16;
          Ob[idx] = f2b(acc[mi][ni][r]);
        }
  }
}

// ---------------- RoPE in-place on q,k slices of qkv (bf16) ----------------
__global__ void rope_kernel(u16* qkv, const int* hp, const int* wp){
  const int W = wp[0], HH = hp[0];
  int idx = blockIdx.x*256 + threadIdx.x;
  if(idx >= M_*H_*48) return;
  const int d = idx % 48;
  int t1 = idx / 48;
  const int h = t1 & 7;
  const int m = t1 >> 3;
  const int s = m & (S_-1);
  const int xc = s % W;
  const int y  = (s / W) % HH;
  const int tf = s / (W*HH);
  float pos1, pos2;
  {
    int blk1 = d >> 5;            // 0 or 1
    int blk2 = (d+48) >> 5;       // 1 or 2
    pos1 = (float)(blk1==0 ? xc : (blk1==1 ? y : tf));
    pos2 = (float)(blk2==0 ? xc : (blk2==1 ? y : tf));
  }
  float a1 = pos1 * __powf(10000.0f, -(float)(d & 15) * (1.0f/16.0f));
  float a2 = pos2 * __powf(10000.0f, -(float)((d+48) & 15) * (1.0f/16.0f));
  float s1, c1, s2, c2;
  __sincosf(a1, &s1, &c1);
  __sincosf(a2, &s2, &c2);
  size_t base = (size_t)m * N3 + h*DH;
  #pragma unroll
  for(int part=0; part<2; part++){
    u16* p = qkv + base + (size_t)part*C_;
    float x1 = b2f(p[d]), x2 = b2f(p[d+48]);
    p[d]    = f2b(x1*c1 - x2*s1);
    p[d+48] = f2b(x2*c2 + x1*s2);
  }
}

// ---------------- V transpose: src rows (b*seq+s, stride) col (colOff+h*DH+d) -> dst[(bh*DH+d)*seq + s] ----------------
__global__ __launch_bounds__(256) void vt_kernel(const u16* __restrict__ src, u16* __restrict__ dst,
                                                 int rowStride, int colOff, int seqLen){
  const int bh = blockIdx.y, b = bh >> 3, h = bh & 7;
  const int s0 = blockIdx.x*64;
  __shared__ u16 t[64][DH+8];
  const int tid = threadIdx.x;
  #pragma unroll
  for(int i=0;i<24;i++){
    int e = tid + i*256; int si = e/DH, d = e - si*DH;
    t[si][d] = src[(size_t)(b*seqLen + s0+si)*rowStride + colOff + h*DH + d];
  }
  __syncthreads();
  #pragma unroll
  for(int i=0;i<24;i++){
    int e = tid + i*256; int d = e >> 6, si = e & 63;
    dst[((size_t)bh*DH + d)*seqLen + s0 + si] = t[si][d];
  }
}

// ---------------- Flash attention (self w/ causal, or cross), LDS-staged K/V, prefetch pipeline ----------------
__global__ __launch_bounds__(256,4) void attn_kernel(
    const u16* __restrict__ qp, int qStride, int qOff,
    const u16* __restrict__ kp, int kStride, int kOff,
    const u16* __restrict__ vt,   // (bh, DH, kvLen)
    u16* __restrict__ op,         // (B*S, C) at col h*DH
    int kvLen, int causal)
{
  __shared__ __align__(16) u16 Ks[64][104];   // 64 kv rows x 96 d (pad->104)
  __shared__ __align__(16) u16 Vs[DH][72];    // 96 d rows  x 64 kv (pad->72)
  __shared__ __align__(16) u16 Plds[4][16][72];
  const int bh = blockIdx.y, b = bh >> 3, h = bh & 7;
  int qt = blockIdx.x;
  if(causal && (blockIdx.y & 8)) qt = gridDim.x - 1 - qt;   // pair long+short on a CU
  const int q0 = qt * 64;
  const int tid = threadIdx.x;
  const int lane = tid & 63, w = tid >> 6;
  const int l15 = lane & 15, lg = lane >> 4, lk = lg << 3;
  const int qrow_base = q0 + w*16;
  const float scale = 0.1020620726159658f;  // 96^-0.5

  // Q fragments (held in regs whole kernel)
  bf16x8 qf[3];
  {
    const size_t qb = (size_t)(b*S_ + qrow_base + l15) * qStride + qOff + h*DH;
    #pragma unroll
    for(int ks=0;ks<3;ks++) qf[ks] = *(const bf16x8*)(qp + qb + ks*32 + lk);
  }

  // staging coordinates: 768 16B-chunks per tile for K (64x96) and V (96x64)
  int krow[3], kcol[3], vrow[3], vcol[3];
  #pragma unroll
  for(int r=0;r<3;r++){
    int c = r*256 + tid;
    krow[r] = c/12; kcol[r] = (c - krow[r]*12)*8;
    vrow[r] = c>>3; vcol[r] = (c&7)*8;
  }
  const u16* kbase = kp + (size_t)b*kvLen*kStride + kOff + h*DH;
  const u16* vbase = vt + (size_t)bh*DH*kvLen;

  const int kvEnd = causal ? (q0 + 64) : kvLen;
  const int nT = kvEnd >> 6;

  uint4 kreg[3], vreg[3];
  // prologue: tile 0 -> LDS
  #pragma unroll
  for(int r=0;r<3;r++){
    kreg[r] = *(const uint4*)(kbase + (size_t)krow[r]*kStride + kcol[r]);
    vreg[r] = *(const uint4*)(vbase + (size_t)vrow[r]*kvLen + vcol[r]);
  }
  #pragma unroll
  for(int r=0;r<3;r++){
    *(uint4*)(&Ks[krow[r]][kcol[r]]) = kreg[r];
    *(uint4*)(&Vs[vrow[r]][vcol[r]]) = vreg[r];
  }
  __syncthreads();

  f32x4 oacc[6] = {};
  float mrow[4], lrow[4];
  #pragma unroll
  for(int r=0;r<4;r++){ mrow[r] = -3e38f; lrow[r] = 0.f; }

  for(int t=0; t<nT; t++){
    const int kv0 = t << 6;
    if(t+1 < nT){  // prefetch next tile into regs (latency hides under compute)
      #pragma unroll
      for(int r=0;r<3;r++){
        kreg[r] = *(const uint4*)(kbase + (size_t)(kv0+64+krow[r])*kStride + kcol[r]);
        vreg[r] = *(const uint4*)(vbase + (size_t)vrow[r]*kvLen + kv0+64 + vcol[r]);
      }
    }
    // === QK^T from LDS ===
    f32x4 sacc[4] = {};
    #pragma unroll
    for(int nt=0;nt<4;nt++){
      #pragma unroll
      for(int ks=0;ks<3;ks++){
        bf16x8 kf = *(const bf16x8*)(&Ks[nt*16+l15][ks*32+lk]);
        sacc[nt] = __builtin_amdgcn_mfma_f32_16x16x32_bf16(qf[ks], kf, sacc[nt], 0,0,0);
      }
    }
    // === mask + online softmax ===
    const bool doMask = (causal != 0) && (kv0 + 64 > qrow_base);
    float mt[4];
    #pragma unroll
    for(int r=0;r<4;r++) mt[r] = -3e38f;
    #pragma unroll
    for(int nt=0;nt<4;nt++)
      #pragma unroll
      for(int r=0;r<4;r++){
        float v = sacc[nt][r] * scale;
        if(doMask && (kv0 + nt*16 + l15 > qrow_base + (lg<<2) + r)) v = -3e38f;
        sacc[nt][r] = v;
        mt[r] = fmaxf(mt[r], v);
      }
    #pragma unroll
    for(int r=0;r<4;r++){
      #pragma unroll
      for(int off=1; off<16; off<<=1) mt[r] = fmaxf(mt[r], __shfl_xor(mt[r], off));
    }
    float al[4], rs[4];
    #pragma unroll
    for(int r=0;r<4;r++){
      float mn = fmaxf(mrow[r], mt[r]);
      al[r] = __expf(mrow[r] - mn);
      mrow[r] = mn;
      rs[r] = 0.f;
    }
    #pragma unroll
    for(int nt=0;nt<4;nt++)
      #pragma unroll
      for(int r=0;r<4;r++){
        float pv = __expf(sacc[nt][r] - mrow[r]);
        sacc[nt][r] = pv;
        rs[r] += pv;
      }
    #pragma unroll
    for(int r=0;r<4;r++){
      #pragma unroll
      for(int off=1; off<16; off<<=1) rs[r] += __shfl_xor(rs[r], off);
      lrow[r] = lrow[r]*al[r] + rs[r];
    }
    #pragma unroll
    for(int n=0;n<6;n++)
      #pragma unroll
      for(int r=0;r<4;r++) oacc[n][r] *= al[r];
    // === P -> LDS (padded, ~conflict-free) -> PV from LDS ===
    #pragma unroll
    for(int nt=0;nt<4;nt++)
      #pragma unroll
      for(int r=0;r<4;r++)
        Plds[w][(lg<<2)+r][nt*16+l15] = f2b(sacc[nt][r]);
    #pragma unroll
    for(int kk=0;kk<2;kk++){
      bf16x8 pf = *(const bf16x8*)(&Plds[w][l15][kk*32 + lk]);
      #pragma unroll
      for(int n=0;n<6;n++){
        bf16x8 vf = *(const bf16x8*)(&Vs[n*16+l15][kk*32+lk]);
        oacc[n] = __builtin_amdgcn_mfma_f32_16x16x32_bf16(pf, vf, oacc[n], 0,0,0);
      }
    }
    __syncthreads();               // all waves done reading Ks/Vs tile t
    if(t+1 < nT){
      #pragma unroll
      for(int r=0;r<3;r++){        // commit prefetched tile t+1
        *(uint4*)(&Ks[krow[r]][kcol[r]]) = kreg[r];
        *(uint4*)(&Vs[vrow[r]][vcol[r]]) = vreg[r];
      }
      __syncthreads();
    }
  }
  #pragma unroll
  for(int n=0;n<6;n++)
    #pragma unroll
    for(int r=0;r<4;r++){
      const int qq = qrow_base + (lg<<2) + r;
      op[(size_t)(b*S_ + qq)*C_ + h*DH + n*16 + l15] = f2b(oacc[n][r] / lrow[r]);
    }
}

// ---------------- SiLU(gate) * up from fused (M, 2I) buffer -> (M, I) bf16, 8-wide ----------------
__global__ void silu_kernel(const u16* __restrict__ gu, u16* __restrict__ obuf, int n8){
  int i = blockIdx.x*256 + threadIdx.x;
  if(i >= n8) return;
  int m = i / (I_/8), c = i - m*(I_/8);
  const uint4 g = *(const uint4*)(gu + (size_t)m*(2*I_) + c*8);
  const uint4 u = *(const uint4*)(gu + (size_t)m*(2*I_) + I_ + c*8);
  const u16* gp = (const u16*)&g; const u16* up = (const u16*)&u;
  uint4 o;
  u16* opw = (u16*)&o;
  #pragma unroll
  for(int j=0;j<8;j++){
    float xg = b2f(gp[j]), yu = b2f(up[j]);
    opw[j] = f2b(xg / (1.0f + __expf(-xg)) * yu);
  }
  *(uint4*)(obuf + (size_t)i*8) = o;
}

extern "C" void kernel_launch(void* const* d_in, const int* in_sizes, int n_in,
                              void* d_out, int out_size, void* d_ws, size_t ws_size,
                              hipStream_t stream)
{
  (void)in_sizes; (void)n_in; (void)out_size;
  const float* x    = (const float*)d_in[0];
  const float* ctxF = (const float*)d_in[1];
  const float* wqkvF= (const float*)d_in[2];
  const float* waoF = (const float*)d_in[3];
  const float* ln1g = (const float*)d_in[4];
  const float* ln1b = (const float*)d_in[5];
  const float* wqcF = (const float*)d_in[6];
  const float* wkcF = (const float*)d_in[7];
  const float* wvcF = (const float*)d_in[8];
  const float* wcoF = (const float*)d_in[9];
  const float* ln2g = (const float*)d_in[10];
  const float* ln2b = (const float*)d_in[11];
  const float* wgF  = (const float*)d_in[12];
  const float* wuF  = (const float*)d_in[13];
  const float* wdF  = (const float*)d_in[14];
  const float* ln3g = (const float*)d_in[15];
  const float* ln3b = (const float*)d_in[16];
  const int* hgt = (const int*)d_in[17];
  const int* wid = (const int*)d_in[18];
  float* out = (float*)d_out;

  char* base = (char*)d_ws;
  size_t off = 0;
  auto alloc = [&](size_t bytes)->void*{
    void* r = base + off;
    off += (bytes + 255) & ~(size_t)255;
    return r;
  };
  u16* wqkvT = (u16*)alloc((size_t)N3*C_*2);
  u16* waoT  = (u16*)alloc((size_t)C_*C_*2);
  u16* wqcT  = (u16*)alloc((size_t)C_*C_*2);
  u16* wkvcT = (u16*)alloc((size_t)2*C_*C_*2);   // wk_c rows then wv_c rows, (1536, 768)
  u16* wcoT  = (u16*)alloc((size_t)C_*C_*2);
  u16* wguT  = (u16*)alloc((size_t)2*I_*C_*2);   // w_gate rows then w_up rows, (6144, 768)
  u16* wdT   = (u16*)alloc((size_t)C_*I_*2);
  u16* ctxb  = (u16*)alloc((size_t)B_*CTX*C_*2);
  u16* xn    = (u16*)alloc((size_t)M_*C_*2);
  u16* gateb = (u16*)alloc((size_t)M_*I_*2);
  float* x1  = (float*)alloc((size_t)M_*C_*4);
  float* x2  = (float*)alloc((size_t)M_*C_*4);
  // transient union region: {qkvb, vtb, obuf, qcb, kvcb, vctb} reused later by gub
  char* uni  = (char*)alloc((size_t)M_*2*I_*2);  // 50.33 MB
  u16* qkvb = (u16*)uni;                                      // 18.87 MB
  u16* vtb  = (u16*)(uni + 18874368);                         //  6.29 MB
  u16* obuf = (u16*)(uni + 18874368 + 1*6291456);             //  6.29 MB
  u16* qcb  = (u16*)(uni + 18874368 + 2*6291456);             //  6.29 MB
  u16* kvcb = (u16*)(uni + 18874368 + 3*6291456);             //  0.79 MB
  u16* vctb = (u16*)(uni + 18874368 + 3*6291456 + 786432);    //  0.39 MB
  u16* gub  = (u16*)uni;                                      // 50.33 MB (MLP phase only)
  if(off > ws_size) return;  // workspace too small -> visible failure

  dim3 blk(256);
  // weight conversion (bf16, transposed to (N,K))
  wconv_kernel<<<dim3(N3/32, C_/32), blk, 0, stream>>>(wqkvF, wqkvT, C_, N3);
  wconv_kernel<<<dim3(C_/32, C_/32), blk, 0, stream>>>(waoF, waoT, C_, C_);
  wconv_kernel<<<dim3(C_/32, C_/32), blk, 0, stream>>>(wqcF, wqcT, C_, C_);
  wconv_kernel<<<dim3(C_/32, C_/32), blk, 0, stream>>>(wkcF, wkvcT, C_, C_);
  wconv_kernel<<<dim3(C_/32, C_/32), blk, 0, stream>>>(wvcF, wkvcT + (size_t)C_*C_, C_, C_);
  wconv_kernel<<<dim3(C_/32, C_/32), blk, 0, stream>>>(wcoF, wcoT, C_, C_);
  wconv_kernel<<<dim3(I_/32, C_/32), blk, 0, stream>>>(wgF, wguT, C_, I_);
  wconv_kernel<<<dim3(I_/32, C_/32), blk, 0, stream>>>(wuF, wguT + (size_t)I_*C_, C_, I_);
  wconv_kernel<<<dim3(C_/32, I_/32), blk, 0, stream>>>(wdF, wdT, I_, C_);
  cvt_kernel<<<dim3((B_*CTX*C_+255)/256), blk, 0, stream>>>(ctxF, ctxb, B_*CTX*C_);

  // ---- self attention ----
  ln_kernel<<<dim3(M_), blk, 0, stream>>>(x, ln1g, ln1b, xn);
  gemm_kernel<<<dim3(N3/128, M_/128), blk, 0, stream>>>(xn, wqkvT, qkvb, nullptr, nullptr, M_, N3, C_, 0);
  rope_kernel<<<dim3((M_*H_*48+255)/256), blk, 0, stream>>>(qkvb, hgt, wid);
  vt_kernel<<<dim3(S_/64, B_*H_), blk, 0, stream>>>(qkvb, vtb, N3, 2*C_, S_);
  attn_kernel<<<dim3(S_/64, B_*H_), blk, 0, stream>>>(qkvb, N3, 0, qkvb, N3, C_, vtb, obuf, S_, 1);
  gemm_kernel<<<dim3(C_/128, M_/128), blk, 0, stream>>>(obuf, waoT, nullptr, x1, x, M_, C_, C_, 1);

  // ---- cross attention ----
  ln_kernel<<<dim3(M_), blk, 0, stream>>>(x1, ln2g, ln2b, xn);
  gemm_kernel<<<dim3(C_/128, M_/128), blk, 0, stream>>>(xn, wqcT, qcb, nullptr, nullptr, M_, C_, C_, 0);
  gemm_kernel<<<dim3(2*C_/128, (B_*CTX)/128), blk, 0, stream>>>(ctxb, wkvcT, kvcb, nullptr, nullptr, B_*CTX, 2*C_, C_, 0);
  vt_kernel<<<dim3(CTX/64, B_*H_), blk, 0, stream>>>(kvcb, vctb, 2*C_, C_, CTX);
  attn_kernel<<<dim3(S_/64, B_*H_), blk, 0, stream>>>(qcb, C_, 0, kvcb, 2*C_, 0, vctb, obuf, CTX, 0);
  gemm_kernel<<<dim3(C_/128, M_/128), blk, 0, stream>>>(obuf, wcoT, nullptr, x2, x1, M_, C_, C_, 1);

  // ---- MLP ----
  ln_kernel<<<dim3(M_), blk, 0, stream>>>(x2, ln3g, ln3b, xn);
  gemm_kernel<<<dim3(2*I_/128, M_/128), blk, 0, stream>>>(xn, wguT, gub, nullptr, nullptr, M_, 2*I_, C_, 0);
  silu_kernel<<<dim3(M_*I_/8/256), blk, 0, stream>>>(gub, gateb, M_*I_/8);
  gemm_kernel<<<dim3(C_/128, M_/128), blk, 0, stream>>>(gateb, wdT, nullptr, out, x2, M_, C_, I_, 1);
}